// Round 10
// baseline (3484.533 us; speedup 1.0000x reference)
//
#include <hip/hip_runtime.h>
#include <hip/hip_fp16.h>
#include <stdint.h>

typedef _Float16 f16;
typedef _Float16 f16x8 __attribute__((ext_vector_type(8)));
typedef _Float16 f16x4 __attribute__((ext_vector_type(4)));
typedef float f32x4 __attribute__((ext_vector_type(4)));

#define TSTEPS 512
#define NBW 256       // worker blocks (== CUs); block NBW is the barrier server
#define NT 512        // 8 waves
#define GQ 2          // batch groups (staggered pipelines)
#define GROWS 16      // batch rows per group

__device__ __forceinline__ float sigm(float v) { return 1.0f / (1.0f + __expf(-v)); }

// Coherent (L2-bypassing, memory-side-L3) accesses for cross-XCD exchange.
__device__ __forceinline__ void ld_coh(f16x8& d, const f16* p) {
  asm volatile("global_load_dwordx4 %0, %1, off sc0 sc1" : "=v"(d) : "v"(p));
}
__device__ __forceinline__ void ld_plain(f16x8& d, const f16* p) {
  asm volatile("global_load_dwordx4 %0, %1, off" : "=v"(d) : "v"(p));
}
__device__ __forceinline__ void st_coh_f16(f16* p, f16 v) {
  asm volatile("global_store_short %0, %1, off sc0 sc1" :: "v"(p), "v"(v) : "memory");
}
__device__ __forceinline__ void st_coh_u32(unsigned* p, unsigned v) {
  asm volatile("global_store_dword %0, %1, off sc0 sc1" :: "v"(p), "v"(v) : "memory");
}
__device__ __forceinline__ uint4 ld_coh_u4(const unsigned* p) {
  uint4 d;
  asm volatile("global_load_dwordx4 %0, %1, off sc0 sc1" : "=v"(d) : "v"(p));
  return d;
}
__device__ __forceinline__ unsigned ld_coh_u32(const unsigned* p) {
  unsigned d;
  asm volatile("global_load_dword %0, %1, off sc0 sc1" : "=v"(d) : "v"(p));
  return d;
}

// Batch-staggered (G=2) persistent 2-layer subLSTM, weights in registers.
// Per group g: R8's proven protocol — workers post flags[g][bid], a release
// point posts gen[g], workers gate each group-step on gen[g]. The release is
// REDUNDANT: a dedicated server block scans+posts, AND block 0's wave 0
// self-heals by scanning inline if gen is late (monotonic idempotent stores,
// so the race is harmless). launch_bounds(NT,4) guarantees 2 blocks/CU so the
// 257th (server) block is co-resident. Every poll: rule #18.
template<int USE_X16>
__global__ __launch_bounds__(NT, 4)
void sublstm_persistent(const float* __restrict__ x,
                        const float* __restrict__ wih0, const float* __restrict__ whh0,
                        const float* __restrict__ b0,
                        const float* __restrict__ wih1, const float* __restrict__ whh1,
                        const float* __restrict__ b1,
                        const f16* __restrict__ x16,
                        f16* __restrict__ h1buf, f16* __restrict__ h2buf,
                        unsigned* __restrict__ bar,
                        float* __restrict__ out)
{
  const int bid   = blockIdx.x;
  const int tid   = threadIdx.x;
  const int lane  = tid & 63;
  const int w     = tid >> 6;

  // ---------- barrier server block: scan flags -> release gen, per group ----
  if (bid == NBW) {
    if (w < GQ) {
      const int g = w;
      const unsigned* fp = bar + g * 256 + (lane << 2);
      for (unsigned kk = 1; kk <= (unsigned)TSTEPS; ++kk) {
        while (true) {
          uint4 d = ld_coh_u4(fp);
          asm volatile("s_waitcnt vmcnt(0)" ::: "memory");
          __builtin_amdgcn_sched_barrier(0);
          if (__all(d.x >= kk && d.y >= kk && d.z >= kk && d.w >= kk)) break;
          __builtin_amdgcn_s_sleep(1);
        }
        if (lane == 0) st_coh_u32(bar + 768 + g * 16, kk);
      }
    }
    return;
  }

  // ---------- worker blocks ----------
  __shared__ float red[8][GROWS][36];   // per-wave partials (pad 36: <=2-way = free)
  __shared__ float gatesS[GROWS][36];
  __shared__ float biasS[32];

  const int layer = bid >> 7;
  const int n     = bid & 127;
  const int c15   = lane & 15;
  const int g4    = lane >> 4;

  const float* wih = layer ? wih1 : wih0;
  const float* whh = layer ? whh1 : whh0;
  const float* bb  = layer ? b1   : b0;

  // one-time: weight slice -> registers (fp32 -> fp16); wave w owns K-octant
  const int kbase = w * 256 + g4 * 8;
  f16x8 breg[2][8];
  #pragma unroll
  for (int cc = 0; cc < 2; ++cc) {
    const int col  = cc * 16 + c15;
    const int gate = ((col >> 3) << 10) + (n << 3) + (col & 7);
    const float* wr = (w < 4) ? (wih + (size_t)gate * 1024 + kbase)
                              : (whh + (size_t)gate * 1024 + (kbase - 1024));
    #pragma unroll
    for (int ks = 0; ks < 8; ++ks) {
      const float4 v0 = *(const float4*)(wr + ks * 32);
      const float4 v1 = *(const float4*)(wr + ks * 32 + 4);
      breg[cc][ks] = (f16x8){(f16)v0.x,(f16)v0.y,(f16)v0.z,(f16)v0.w,
                             (f16)v1.x,(f16)v1.y,(f16)v1.z,(f16)v1.w};
    }
  }
  if (tid < 32) biasS[tid] = bb[((tid >> 3) << 10) + (n << 3) + (tid & 7)];
  __syncthreads();

  float c = 0.0f;        // cell state: thread (g=tid>>7, bl, jj) fixed across steps
  f16x8 af[8];

  for (int u = 0; u < (TSTEPS + 1) * GQ; ++u) {
    const int g     = u & 1;
    const int k     = u >> 1;
    const int p_in  = k & 1;
    const int p_out = (k + 1) & 1;
    const bool active = (layer == 0) ? (k < TSTEPS) : (k >= 1);
    const int t = (layer == 0) ? k : (k - 1);

    // x-issue early: no dependency on the gate, latency hides under the poll
    if (active && layer == 0 && w < 4) {
      if (USE_X16) {
        const f16* bp = x16 + ((size_t)t * 32 + g * GROWS + c15) * 1024 + kbase;
        #pragma unroll
        for (int ks = 0; ks < 8; ++ks) ld_plain(af[ks], bp + ks * 32);
      } else {
        const float* bp = x + ((size_t)t * 32 + g * GROWS + c15) * 1024 + kbase;
        #pragma unroll
        for (int ks = 0; ks < 8; ++ks) {
          const float4 v0 = *(const float4*)(bp + ks * 32);
          const float4 v1 = *(const float4*)(bp + ks * 32 + 4);
          af[ks] = (f16x8){(f16)v0.x,(f16)v0.y,(f16)v0.z,(f16)v0.w,
                           (f16)v1.x,(f16)v1.y,(f16)v1.z,(f16)v1.w};
        }
      }
    }

    // group-g gate: gen[g] >= k. Wave 0 polls; block 0's wave 0 also scans the
    // flags itself and posts gen if the server hasn't yet (self-healing).
    if (k >= 1) {
      if (w == 0) {
        unsigned* gp = bar + 768 + g * 16;
        const unsigned kk = (unsigned)k;
        while (true) {
          const unsigned gv = ld_coh_u32(gp);
          asm volatile("s_waitcnt vmcnt(0)" ::: "memory");
          __builtin_amdgcn_sched_barrier(0);
          if (gv >= kk) break;
          if (bid == 0) {
            uint4 d = ld_coh_u4(bar + g * 256 + (lane << 2));
            asm volatile("s_waitcnt vmcnt(0)" ::: "memory");
            __builtin_amdgcn_sched_barrier(0);
            if (__all(d.x >= kk && d.y >= kk && d.z >= kk && d.w >= kk)) {
              if (lane == 0) st_coh_u32(gp, kk);
              break;
            }
          }
          __builtin_amdgcn_s_sleep(1);
        }
      }
      __syncthreads();
    }

    if (active) {
      if (!(layer == 0 && w < 4)) {
        // h-wave: load group-g h slice (coherent; gate ordered it)
        const f16* src; int koff;
        if (layer == 0)   { src = h1buf; koff = kbase - 1024; }
        else if (w < 4)   { src = h1buf; koff = kbase; }
        else              { src = h2buf; koff = kbase - 1024; }
        const f16* bp = src + ((size_t)(g * 2 + p_in) * GROWS + c15) * 1024 + koff;
        #pragma unroll
        for (int ks = 0; ks < 8; ++ks) ld_coh(af[ks], bp + ks * 32);
      }
      asm volatile("s_waitcnt vmcnt(0)" ::: "memory");
      __builtin_amdgcn_sched_barrier(0);

      f32x4 acc[2] = {{0,0,0,0},{0,0,0,0}};
      #pragma unroll
      for (int ks = 0; ks < 8; ++ks)
        #pragma unroll
        for (int cc = 0; cc < 2; ++cc)
          acc[cc] = __builtin_amdgcn_mfma_f32_16x16x32_f16(af[ks], breg[cc][ks], acc[cc], 0, 0, 0);

      // C frag: row = g4*4 + r (group-local 0..15), col = cc*16 + c15
      #pragma unroll
      for (int cc = 0; cc < 2; ++cc)
        #pragma unroll
        for (int r = 0; r < 4; ++r)
          red[w][g4 * 4 + r][cc * 16 + c15] = acc[cc][r];
    }
    __syncthreads();

    if (active) {
      // reduce 8 K-octant partials: 512 entries, one per thread
      const int b = tid >> 5, col = tid & 31;
      float tot = biasS[col];
      #pragma unroll
      for (int ww = 0; ww < 8; ++ww) tot += red[ww][b][col];
      gatesS[b][col] = sigm(tot);
    }
    __syncthreads();

    if (active && (tid >> 7) == g) {
      const int lt = tid & 127;
      const int bl = lt >> 3, jj = lt & 7;
      const float ig = gatesS[bl][jj];
      const float og = gatesS[bl][8 + jj];
      const float zg = gatesS[bl][16 + jj];
      const float fg = gatesS[bl][24 + jj];
      c = c * fg + zg - ig;
      const float h = sigm(c) - og;
      const int j = (n << 3) + jj;
      f16* hb = ((layer == 0) ? h1buf : h2buf)
              + ((size_t)(g * 2 + p_out) * GROWS + bl) * 1024 + j;
      st_coh_f16(hb, (f16)h);
      if (layer == 1) out[((size_t)t * 32 + g * GROWS + bl) * 1024 + j] = h;
    }

    // drain h/out stores, then post this block's group-g flag
    asm volatile("s_waitcnt vmcnt(0)" ::: "memory");
    __syncthreads();
    if (tid == 0 && k < TSTEPS) st_coh_u32(bar + g * 256 + bid, (unsigned)(k + 1));
  }
}

__global__ void cvt_x_kernel(const float4* __restrict__ in, f16x4* __restrict__ outv, int n4) {
  int i = blockIdx.x * blockDim.x + threadIdx.x;
  const int stride = gridDim.x * blockDim.x;
  for (; i < n4; i += stride) {
    const float4 v = in[i];
    outv[i] = (f16x4){(f16)v.x, (f16)v.y, (f16)v.z, (f16)v.w};
  }
}

extern "C" void kernel_launch(void* const* d_in, const int* in_sizes, int n_in,
                              void* d_out, int out_size, void* d_ws, size_t ws_size,
                              hipStream_t stream) {
  const float* x    = (const float*)d_in[0];
  const float* wih0 = (const float*)d_in[1];
  const float* whh0 = (const float*)d_in[2];
  const float* b0   = (const float*)d_in[3];
  const float* wih1 = (const float*)d_in[4];
  const float* whh1 = (const float*)d_in[5];
  const float* b1   = (const float*)d_in[6];
  float* out = (float*)d_out;

  const size_t X16B   = (size_t)512 * 32 * 1024 * 2;            // fp16 copy of x
  const size_t HBUFB  = (size_t)GQ * 2 * GROWS * 1024 * 2;      // per layer: [g][phase][16][1024] f16
  const size_t STATEB = 2 * HBUFB + 4096;                       // h1 + h2 + flags/gen

  char* ws = (char*)d_ws;
  const bool use_x16 = ws_size >= X16B + STATEB;
  const size_t soff = use_x16 ? X16B : 0;
  f16* x16        = (f16*)ws;
  f16* h1buf      = (f16*)(ws + soff);
  f16* h2buf      = (f16*)(ws + soff + HBUFB);
  unsigned* bar   = (unsigned*)(ws + soff + 2 * HBUFB);

  // zero h state + flags/gen (ws is poisoned, and graph replays reuse it)
  hipMemsetAsync(ws + soff, 0, STATEB, stream);

  if (use_x16) {
    const int n4 = 512 * 32 * 1024 / 4;
    cvt_x_kernel<<<2048, 256, 0, stream>>>((const float4*)x, (f16x4*)x16, n4);
    sublstm_persistent<1><<<NBW + 1, NT, 0, stream>>>(x, wih0, whh0, b0, wih1, whh1, b1,
                                                      x16, h1buf, h2buf, bar, out);
  } else {
    sublstm_persistent<0><<<NBW + 1, NT, 0, stream>>>(x, wih0, whh0, b0, wih1, whh1, b1,
                                                      x16, h1buf, h2buf, bar, out);
  }
}